// Round 1
// baseline (256.782 us; speedup 1.0000x reference)
//
#include <hip/hip_runtime.h>
#include <stdint.h>

// ---------------------------------------------------------------------------
// QuantBertSelfOutput: out = LayerNorm( hs @ fakequant(W)^T + b + residual )
// Strategy:
//   q = round(W/scale) is integer in [-128,127] -> EXACT in bf16; scale applied
//   in epilogue. hs split into hi+lo bf16 -> fp32-grade accuracy with 2x MFMA.
//   One block covers the FULL output row (BN=1024) so LayerNorm fuses in-block.
// ---------------------------------------------------------------------------

#define D_DIM 1024
#define BM 64
#define BK 64
#define NKT (D_DIM / BK)              // 16 K-steps
#define AROW_B 144                    // bytes per padded A row (64*2 + 16 pad)
#define BYTES_B (D_DIM * BK * 2)      // 131072: B tile [1024 cols][64 k] bf16
#define BYTES_A (BM * AROW_B)         // 9216 per A buffer (hi or lo)
#define LDS_BYTES (BYTES_B + 2 * BYTES_A)   // 149504 < 160 KiB

typedef float f32x4 __attribute__((ext_vector_type(4)));
typedef short s16x8 __attribute__((ext_vector_type(8)));   // 8 x bf16 (4 VGPRs)

__device__ __forceinline__ uint32_t bf16_rne_bits(float x) {
  uint32_t u = __float_as_uint(x);
  return (u + 0x7fffu + ((u >> 16) & 1u)) >> 16;   // round-to-nearest-even
}

// ---------------- prepass: per-output-channel fake-quant of W ----------------
__global__ __launch_bounds__(256) void quantw_kernel(
    const float* __restrict__ W, uint16_t* __restrict__ q,
    float* __restrict__ scale) {
  const int e = blockIdx.x;        // output channel (row of W)
  const int t = threadIdx.x;       // 256 threads, 4 elems each
  __shared__ float redmax[4];
  __shared__ __align__(16) uint16_t qrow[D_DIM];

  float4 w4 = reinterpret_cast<const float4*>(W + (size_t)e * D_DIM)[t];
  float am = fmaxf(fmaxf(fabsf(w4.x), fabsf(w4.y)),
                   fmaxf(fabsf(w4.z), fabsf(w4.w)));
#pragma unroll
  for (int d = 1; d < 64; d <<= 1) am = fmaxf(am, __shfl_xor(am, d));
  if ((t & 63) == 0) redmax[t >> 6] = am;
  __syncthreads();
  am = fmaxf(fmaxf(redmax[0], redmax[1]), fmaxf(redmax[2], redmax[3]));
  float sc = fmaxf(am * (1.0f / 127.0f), 1e-8f);
  if (t == 0) scale[e] = sc;

  float v[4] = {w4.x, w4.y, w4.z, w4.w};
#pragma unroll
  for (int i = 0; i < 4; ++i) {
    // rintf == round-half-even, matches jnp.round; integers are exact in bf16
    float qq = fminf(fmaxf(rintf(v[i] / sc), -128.0f), 127.0f);
    qrow[4 * t + i] = (uint16_t)bf16_rne_bits(qq);
  }
  __syncthreads();
  if (t < 128) {   // copy row out as 16B chunks, plain row-major q[e][k]
    reinterpret_cast<float4*>(q + (size_t)e * D_DIM)[t] =
        reinterpret_cast<const float4*>(qrow)[t];
  }
}

// ---------------- fused GEMM (split-bf16) + bias + residual + LN ------------
__global__ __launch_bounds__(512, 2) void gemm_ln_kernel(
    const float* __restrict__ hs, const float* __restrict__ res,
    const uint16_t* __restrict__ q, const float* __restrict__ scale,
    const float* __restrict__ bias, const float* __restrict__ lnw,
    const float* __restrict__ lnb, float* __restrict__ out) {
  extern __shared__ char lds[];
  // LDS map: [0,131072) B tile; [131072,+9216) A_hi; [140288,+9216) A_lo
  const int tid  = threadIdx.x;
  const int lane = tid & 63;
  const int w    = tid >> 6;        // wave 0..7, owns cols w*128..w*128+127
  const size_t brow = (size_t)blockIdx.x * BM;

  f32x4 acc[4][8] = {};             // [m-frag][n-frag], fp32 accum

  // A staging addressing: thread t loads row t>>3, k-chunk (t&7)*8 (8 floats)
  const int ar  = tid >> 3;
  const int akc = tid & 7;
  const float* ap = hs + (brow + ar) * D_DIM + akc * 8;
  char* ahw = lds + BYTES_B + ar * AROW_B + akc * 16;
  char* alw = ahw + BYTES_A;

  const int l15 = lane & 15;
  const int l4  = lane >> 4;
  const int cbase = w * 128 + l15;  // this lane's base output column

  for (int kt = 0; kt < NKT; ++kt) {
    // ---- A: global fp32 -> hi/lo bf16 split (issued before barrier) ----
    float4 x0 = *reinterpret_cast<const float4*>(ap + kt * 64);
    float4 x1 = *reinterpret_cast<const float4*>(ap + kt * 64 + 4);

    __syncthreads();                 // previous compute done; LDS reusable

    float xs[8] = {x0.x, x0.y, x0.z, x0.w, x1.x, x1.y, x1.z, x1.w};
    union { uint16_t u[8]; float4 f; } hi, lo;
#pragma unroll
    for (int i = 0; i < 8; ++i) {
      uint32_t hb = bf16_rne_bits(xs[i]);
      hi.u[i] = (uint16_t)hb;
      float hf = __uint_as_float(hb << 16);
      lo.u[i] = (uint16_t)bf16_rne_bits(xs[i] - hf);
    }
    *reinterpret_cast<float4*>(ahw) = hi.f;   // padded rows: bank-friendly
    *reinterpret_cast<float4*>(alw) = lo.f;

    // ---- B: q (L2-resident bf16) -> LDS, XOR chunk swizzle (read conflicts
    //      2x -> 1x; writes stay bank-uniform) ----
#pragma unroll
    for (int r = 0; r < 16; ++r) {
      int idx = r * 512 + tid;
      int c = idx >> 3, g = idx & 7;   // col, 16B-chunk within col
      float4 v = *reinterpret_cast<const float4*>(
          q + (size_t)c * D_DIM + kt * 64 + g * 8);
      *reinterpret_cast<float4*>(lds + c * 128 + ((g ^ (c & 7)) * 16)) = v;
    }
    __syncthreads();                 // tile staged

    // ---- compute: 128 MFMA per wave per K-step ----
#pragma unroll
    for (int kk = 0; kk < 2; ++kk) {
      s16x8 ah[4], al[4], bb[8];
      const int aoff = l15 * AROW_B + kk * 64 + l4 * 16;
#pragma unroll
      for (int m = 0; m < 4; ++m) {
        ah[m] = *reinterpret_cast<const s16x8*>(lds + BYTES_B + m * (16 * AROW_B) + aoff);
        al[m] = *reinterpret_cast<const s16x8*>(lds + BYTES_B + BYTES_A + m * (16 * AROW_B) + aoff);
      }
      const int chunk = kk * 4 + l4;
#pragma unroll
      for (int n = 0; n < 8; ++n) {
        int c = cbase + n * 16;
        bb[n] = *reinterpret_cast<const s16x8*>(lds + c * 128 + ((chunk ^ (c & 7)) * 16));
      }
#pragma unroll
      for (int m = 0; m < 4; ++m)
#pragma unroll
        for (int n = 0; n < 8; ++n) {
          acc[m][n] = __builtin_amdgcn_mfma_f32_16x16x32_bf16(ah[m], bb[n], acc[m][n], 0, 0, 0);
          acc[m][n] = __builtin_amdgcn_mfma_f32_16x16x32_bf16(al[m], bb[n], acc[m][n], 0, 0, 0);
        }
    }
  }

  // ---------------- epilogue: scale + bias + residual + LayerNorm ----------
  float scl[8], bs[8], lw[8], lb[8];
#pragma unroll
  for (int n = 0; n < 8; ++n) {
    int c = cbase + n * 16;
    scl[n] = scale[c]; bs[n] = bias[c]; lw[n] = lnw[c]; lb[n] = lnb[c];
  }
  const int g4 = l4 * 4;
  float zs[4][4], zq[4][4];
#pragma unroll
  for (int m = 0; m < 4; ++m)
#pragma unroll
    for (int r = 0; r < 4; ++r) { zs[m][r] = 0.f; zq[m][r] = 0.f; }

  // C/D layout (verified m89): row = (lane>>4)*4 + reg, col = lane&15
#pragma unroll
  for (int m = 0; m < 4; ++m)
#pragma unroll
    for (int r = 0; r < 4; ++r) {
      size_t rowoff = (brow + m * 16 + g4 + r) * D_DIM;
#pragma unroll
      for (int n = 0; n < 8; ++n) {
        float z = acc[m][n][r] * scl[n] + bs[n] + res[rowoff + cbase + n * 16];
        acc[m][n][r] = z;            // keep z in regs for the normalize pass
        zs[m][r] += z;
        zq[m][r] += z * z;
      }
    }

  __syncthreads();                   // LDS tiles dead; reuse for reduction
  float*  redsum = reinterpret_cast<float*>(lds);          // [8][64]
  float*  redsq  = redsum + 512;                           // [8][64]
  float2* stats  = reinterpret_cast<float2*>(lds + 4096);  // [64] (mu, rstd)

#pragma unroll
  for (int m = 0; m < 4; ++m)
#pragma unroll
    for (int r = 0; r < 4; ++r) {
      float s = zs[m][r], ss = zq[m][r];
#pragma unroll
      for (int d = 1; d < 16; d <<= 1) {   // reduce over the 16 col-lanes
        s  += __shfl_xor(s, d);
        ss += __shfl_xor(ss, d);
      }
      if (l15 == 0) {
        redsum[w * 64 + m * 16 + g4 + r] = s;
        redsq [w * 64 + m * 16 + g4 + r] = ss;
      }
    }
  __syncthreads();
  if (tid < 64) {                    // one thread per row: combine 8 waves
    float s = 0.f, ss = 0.f;
#pragma unroll
    for (int ww = 0; ww < 8; ++ww) { s += redsum[ww * 64 + tid]; ss += redsq[ww * 64 + tid]; }
    float mu  = s * (1.0f / 1024.0f);
    float var = ss * (1.0f / 1024.0f) - mu * mu;
    stats[tid] = make_float2(mu, rsqrtf(var + 1e-12f));
  }
  __syncthreads();

#pragma unroll
  for (int m = 0; m < 4; ++m)
#pragma unroll
    for (int r = 0; r < 4; ++r) {
      float2 st = stats[m * 16 + g4 + r];
      size_t rowoff = (brow + m * 16 + g4 + r) * D_DIM;
#pragma unroll
      for (int n = 0; n < 8; ++n) {
        out[rowoff + cbase + n * 16] =
            (acc[m][n][r] - st.x) * st.y * lw[n] + lb[n];
      }
    }
}

// ---------------------------------------------------------------------------
extern "C" void kernel_launch(void* const* d_in, const int* in_sizes, int n_in,
                              void* d_out, int out_size, void* d_ws, size_t ws_size,
                              hipStream_t stream) {
  const float* hs  = (const float*)d_in[0];   // hidden_states [M,1024] fp32
  const float* res = (const float*)d_in[1];   // input_tensor  [M,1024] fp32
  const float* W   = (const float*)d_in[2];   // [1024,1024] fp32
  const float* b   = (const float*)d_in[3];   // [1024]
  const float* lnw = (const float*)d_in[4];   // [1024]
  const float* lnb = (const float*)d_in[5];   // [1024]
  float* out = (float*)d_out;

  // workspace: scale[1024] fp32 @0, q bf16 [1024][1024] @4096 (2.004 MiB)
  float*    scale = (float*)d_ws;
  uint16_t* q     = (uint16_t*)((char*)d_ws + 4096);

  const int M = in_sizes[0] / D_DIM;          // 16384

  // opt-in for 146 KiB dynamic LDS (idempotent; not a stream op, capture-safe)
  hipFuncSetAttribute((const void*)gemm_ln_kernel,
                      hipFuncAttributeMaxDynamicSharedMemorySize, LDS_BYTES);

  quantw_kernel<<<dim3(D_DIM), dim3(256), 0, stream>>>(W, q, scale);
  gemm_ln_kernel<<<dim3(M / BM), dim3(512), LDS_BYTES, stream>>>(
      hs, res, q, scale, b, lnw, lnb, out);
}